// Round 7
// baseline (742.331 us; speedup 1.0000x reference)
//
#include <hip/hip_runtime.h>
#include <stdint.h>

// ---------------------------------------------------------------------------
// GCN 5-layer, N=50000, E=600000.  out = ((Anorm @ h) @ W) + b per layer.
// Activations: f16 hi/lo (22-bit mantissa). Packed (h,l) pairs for the agg
// gather (one 1KB stream/row, request-BW-bound at ~6.7 TB/s = ceiling);
// hi/lo planes for GEMM staging. R6 lesson: do NOT fuse agg+GEMM (occupancy).
// GEMM = f16x3 split MFMA, BM=128 x BN=256 (B staged once per 128 rows).
// ---------------------------------------------------------------------------

typedef _Float16 v8h __attribute__((ext_vector_type(8)));
typedef _Float16 v4h __attribute__((ext_vector_type(4)));
typedef _Float16 v2h __attribute__((ext_vector_type(2)));
typedef float v4f __attribute__((ext_vector_type(4)));

// ---------------- CSR build ----------------
__global__ void count_edges(const int* __restrict__ dst, int E, int* __restrict__ counts) {
    int i = blockIdx.x * blockDim.x + threadIdx.x;
    if (i < E) atomicAdd(&counts[dst[i]], 1);
}

__global__ void block_sums(const int* __restrict__ counts, int n, int* __restrict__ partial) {
    __shared__ int red[256];
    int t = threadIdx.x;
    int i = blockIdx.x * 256 + t;
    red[t] = (i < n) ? counts[i] : 0;
    __syncthreads();
    #pragma unroll
    for (int off = 128; off > 0; off >>= 1) {
        if (t < off) red[t] += red[t + off];
        __syncthreads();
    }
    if (t == 0) partial[blockIdx.x] = red[0];
}

__global__ void scan_partials(int* __restrict__ partial, int nb, int* __restrict__ row_ptr, int n) {
    __shared__ int s[256];
    int t = threadIdx.x;
    int v = (t < nb) ? partial[t] : 0;
    s[t] = v;
    __syncthreads();
    #pragma unroll
    for (int off = 1; off < 256; off <<= 1) {
        int u = (t >= off) ? s[t - off] : 0;
        __syncthreads();
        s[t] += u;
        __syncthreads();
    }
    if (t < nb) partial[t] = s[t] - v;
    if (t == 0) row_ptr[n] = s[255];
}

__global__ void scan_final(const int* __restrict__ counts, int n, const int* __restrict__ partial,
                           int* __restrict__ row_ptr, float* __restrict__ dinv,
                           int* __restrict__ fill) {
    __shared__ int s[256];
    int t = threadIdx.x;
    int i = blockIdx.x * 256 + t;
    int c = (i < n) ? counts[i] : 0;
    s[t] = c;
    __syncthreads();
    #pragma unroll
    for (int off = 1; off < 256; off <<= 1) {
        int u = (t >= off) ? s[t - off] : 0;
        __syncthreads();
        s[t] += u;
        __syncthreads();
    }
    if (i < n) {
        row_ptr[i] = partial[blockIdx.x] + s[t] - c;
        dinv[i] = rsqrtf((float)(c + 1));
        fill[i] = 0;
    }
}

__global__ void build_csr(const int* __restrict__ src, const int* __restrict__ dst, int E,
                          const int* __restrict__ row_ptr, int* __restrict__ fill,
                          int2* __restrict__ esw, const float* __restrict__ dinv) {
    int i = blockIdx.x * blockDim.x + threadIdx.x;
    if (i < E) {
        int d = dst[i];
        int s = src[i];
        int pos = row_ptr[d] + atomicAdd(&fill[d], 1);
        esw[pos] = make_int2(s, __float_as_int(dinv[s]));
    }
}

// ---------------- weight split+transpose (all 5 layers, one launch) ----------------
struct SplitArgs {
    const float* W[5];
    _Float16* Wh[5];
    _Float16* Wl[5];
    int lgFI[5];
    int FO[5];
    int off[6];
};

__global__ void split_all(SplitArgs a) {
    int i = blockIdx.x * 256 + threadIdx.x;
    #pragma unroll
    for (int l = 0; l < 5; ++l) {
        if (i >= a.off[l] && i < a.off[l + 1]) {
            int j = i - a.off[l];
            int FI = 1 << a.lgFI[l];
            int c = j >> a.lgFI[l];
            int k = j & (FI - 1);
            float v = a.W[l][(size_t)k * a.FO[l] + c];
            _Float16 h = (_Float16)v;
            a.Wh[l][j] = h;
            a.Wl[l][j] = (_Float16)(v - (float)h);
        }
    }
}

// ---------------- aggregation: packed-in (L2..L4), F=256 ----------------
__global__ __launch_bounds__(256) void agg_packed(
    const _Float16* __restrict__ inP, const int* __restrict__ row_ptr,
    const int2* __restrict__ esw, const float* __restrict__ dinv,
    _Float16* __restrict__ outH, _Float16* __restrict__ outL, int n) {
    int wid = (blockIdx.x * blockDim.x + threadIdx.x) >> 6;
    if (wid >= n) return;
    const int lane = threadIdx.x & 63;
    int e = __builtin_amdgcn_readfirstlane(row_ptr[wid]);
    const int end = __builtin_amdgcn_readfirstlane(row_ptr[wid + 1]);
    const float dd = dinv[wid];
    const _Float16* rb = inP + (size_t)lane * 8;
    float a0, a1, a2, a3;
    {
        v8h p = *(const v8h*)(rb + (size_t)wid * 512);
        a0 = dd * ((float)p[0] + (float)p[1]);
        a1 = dd * ((float)p[2] + (float)p[3]);
        a2 = dd * ((float)p[4] + (float)p[5]);
        a3 = dd * ((float)p[6] + (float)p[7]);
    }
#define GTH(q) (*(const v8h*)(rb + (size_t)(q).x * 512))
#define ACC(b, w)                                  \
    a0 += (w) * ((float)(b)[0] + (float)(b)[1]);   \
    a1 += (w) * ((float)(b)[2] + (float)(b)[3]);   \
    a2 += (w) * ((float)(b)[4] + (float)(b)[5]);   \
    a3 += (w) * ((float)(b)[6] + (float)(b)[7]);
    for (; e + 8 <= end; e += 8) {
        int2 q0 = esw[e + 0], q1 = esw[e + 1], q2 = esw[e + 2], q3 = esw[e + 3];
        int2 q4 = esw[e + 4], q5 = esw[e + 5], q6 = esw[e + 6], q7 = esw[e + 7];
        v8h b0 = GTH(q0), b1 = GTH(q1), b2 = GTH(q2), b3 = GTH(q3);
        v8h b4 = GTH(q4), b5 = GTH(q5), b6 = GTH(q6), b7 = GTH(q7);
        ACC(b0, __int_as_float(q0.y)) ACC(b1, __int_as_float(q1.y))
        ACC(b2, __int_as_float(q2.y)) ACC(b3, __int_as_float(q3.y))
        ACC(b4, __int_as_float(q4.y)) ACC(b5, __int_as_float(q5.y))
        ACC(b6, __int_as_float(q6.y)) ACC(b7, __int_as_float(q7.y))
    }
    if (e + 4 <= end) {
        int2 q0 = esw[e + 0], q1 = esw[e + 1], q2 = esw[e + 2], q3 = esw[e + 3];
        v8h b0 = GTH(q0), b1 = GTH(q1), b2 = GTH(q2), b3 = GTH(q3);
        ACC(b0, __int_as_float(q0.y)) ACC(b1, __int_as_float(q1.y))
        ACC(b2, __int_as_float(q2.y)) ACC(b3, __int_as_float(q3.y))
        e += 4;
    }
    if (e < end) {
        const int em = end - 1;
        int e1 = (e + 1 < end) ? e + 1 : em;
        int e2 = (e + 2 < end) ? e + 2 : em;
        int2 q0 = esw[e], q1 = esw[e1], q2 = esw[e2], q3 = esw[em];
        float w0 = __int_as_float(q0.y);
        float w1 = (e + 1 < end) ? __int_as_float(q1.y) : 0.f;
        float w2 = (e + 2 < end) ? __int_as_float(q2.y) : 0.f;
        float w3 = (e + 3 < end) ? __int_as_float(q3.y) : 0.f;
        v8h b0 = GTH(q0), b1 = GTH(q1), b2 = GTH(q2), b3 = GTH(q3);
        ACC(b0, w0) ACC(b1, w1) ACC(b2, w2) ACC(b3, w3)
    }
#undef GTH
#undef ACC
    size_t o = (size_t)wid * 256 + lane * 4;
    float s0 = dd * a0, s1 = dd * a1, s2 = dd * a2, s3 = dd * a3;
    _Float16 h0 = (_Float16)s0, h1 = (_Float16)s1, h2 = (_Float16)s2, h3 = (_Float16)s3;
    *(v4h*)&outH[o] = (v4h){h0, h1, h2, h3};
    *(v4h*)&outL[o] = (v4h){(_Float16)(s0 - (float)h0), (_Float16)(s1 - (float)h1),
                            (_Float16)(s2 - (float)h2), (_Float16)(s3 - (float)h3)};
}

// ---------------- aggregation: f32-in 128 feats (L1) -> hi/lo planes ----------------
__global__ __launch_bounds__(256) void agg_f32_128(
    const float* __restrict__ in, const int* __restrict__ row_ptr,
    const int2* __restrict__ esw, const float* __restrict__ dinv,
    _Float16* __restrict__ outH, _Float16* __restrict__ outL, int n) {
    int wid = (blockIdx.x * blockDim.x + threadIdx.x) >> 6;
    if (wid >= n) return;
    const int lane = threadIdx.x & 63;
    int e = __builtin_amdgcn_readfirstlane(row_ptr[wid]);
    const int end = __builtin_amdgcn_readfirstlane(row_ptr[wid + 1]);
    const float dd = dinv[wid];
    const float* rb = in + (size_t)lane * 2;
    float a0, a1;
    {
        float2 p = *(const float2*)(rb + (size_t)wid * 128);
        a0 = dd * p.x;
        a1 = dd * p.y;
    }
#define GTH(q) (*(const float2*)(rb + (size_t)(q).x * 128))
#define ACC(b, w) a0 += (w) * (b).x; a1 += (w) * (b).y;
    for (; e + 8 <= end; e += 8) {
        int2 q0 = esw[e + 0], q1 = esw[e + 1], q2 = esw[e + 2], q3 = esw[e + 3];
        int2 q4 = esw[e + 4], q5 = esw[e + 5], q6 = esw[e + 6], q7 = esw[e + 7];
        float2 b0 = GTH(q0), b1 = GTH(q1), b2 = GTH(q2), b3 = GTH(q3);
        float2 b4 = GTH(q4), b5 = GTH(q5), b6 = GTH(q6), b7 = GTH(q7);
        ACC(b0, __int_as_float(q0.y)) ACC(b1, __int_as_float(q1.y))
        ACC(b2, __int_as_float(q2.y)) ACC(b3, __int_as_float(q3.y))
        ACC(b4, __int_as_float(q4.y)) ACC(b5, __int_as_float(q5.y))
        ACC(b6, __int_as_float(q6.y)) ACC(b7, __int_as_float(q7.y))
    }
    if (e + 4 <= end) {
        int2 q0 = esw[e + 0], q1 = esw[e + 1], q2 = esw[e + 2], q3 = esw[e + 3];
        float2 b0 = GTH(q0), b1 = GTH(q1), b2 = GTH(q2), b3 = GTH(q3);
        ACC(b0, __int_as_float(q0.y)) ACC(b1, __int_as_float(q1.y))
        ACC(b2, __int_as_float(q2.y)) ACC(b3, __int_as_float(q3.y))
        e += 4;
    }
    if (e < end) {
        const int em = end - 1;
        int e1 = (e + 1 < end) ? e + 1 : em;
        int e2 = (e + 2 < end) ? e + 2 : em;
        int2 q0 = esw[e], q1 = esw[e1], q2 = esw[e2], q3 = esw[em];
        float w0 = __int_as_float(q0.y);
        float w1 = (e + 1 < end) ? __int_as_float(q1.y) : 0.f;
        float w2 = (e + 2 < end) ? __int_as_float(q2.y) : 0.f;
        float w3 = (e + 3 < end) ? __int_as_float(q3.y) : 0.f;
        float2 b0 = GTH(q0), b1 = GTH(q1), b2 = GTH(q2), b3 = GTH(q3);
        ACC(b0, w0) ACC(b1, w1) ACC(b2, w2) ACC(b3, w3)
    }
#undef GTH
#undef ACC
    size_t o = (size_t)wid * 128 + lane * 2;
    float s0 = dd * a0, s1 = dd * a1;
    _Float16 h0 = (_Float16)s0, h1 = (_Float16)s1;
    *(v2h*)&outH[o] = (v2h){h0, h1};
    *(v2h*)&outL[o] = (v2h){(_Float16)(s0 - (float)h0), (_Float16)(s1 - (float)h1)};
}

// ---------------- aggregation: f32-in 64 feats (L5) -> f32 + bias ----------------
__global__ __launch_bounds__(256) void agg_f32_64(
    const float* __restrict__ in, const int* __restrict__ row_ptr,
    const int2* __restrict__ esw, const float* __restrict__ dinv,
    const float* __restrict__ bias, float* __restrict__ outF, int n) {
    int wid = (blockIdx.x * blockDim.x + threadIdx.x) >> 6;
    if (wid >= n) return;
    const int lane = threadIdx.x & 63;
    int e = __builtin_amdgcn_readfirstlane(row_ptr[wid]);
    const int end = __builtin_amdgcn_readfirstlane(row_ptr[wid + 1]);
    const float dd = dinv[wid];
    const float* rb = in + lane;
    float a0 = dd * rb[(size_t)wid * 64];
#define GTH(q) (rb[(size_t)(q).x * 64])
    for (; e + 8 <= end; e += 8) {
        int2 q0 = esw[e + 0], q1 = esw[e + 1], q2 = esw[e + 2], q3 = esw[e + 3];
        int2 q4 = esw[e + 4], q5 = esw[e + 5], q6 = esw[e + 6], q7 = esw[e + 7];
        float b0 = GTH(q0), b1 = GTH(q1), b2 = GTH(q2), b3 = GTH(q3);
        float b4 = GTH(q4), b5 = GTH(q5), b6 = GTH(q6), b7 = GTH(q7);
        a0 += __int_as_float(q0.y) * b0 + __int_as_float(q1.y) * b1;
        a0 += __int_as_float(q2.y) * b2 + __int_as_float(q3.y) * b3;
        a0 += __int_as_float(q4.y) * b4 + __int_as_float(q5.y) * b5;
        a0 += __int_as_float(q6.y) * b6 + __int_as_float(q7.y) * b7;
    }
    if (e + 4 <= end) {
        int2 q0 = esw[e + 0], q1 = esw[e + 1], q2 = esw[e + 2], q3 = esw[e + 3];
        float b0 = GTH(q0), b1 = GTH(q1), b2 = GTH(q2), b3 = GTH(q3);
        a0 += __int_as_float(q0.y) * b0 + __int_as_float(q1.y) * b1;
        a0 += __int_as_float(q2.y) * b2 + __int_as_float(q3.y) * b3;
        e += 4;
    }
    if (e < end) {
        const int em = end - 1;
        int e1 = (e + 1 < end) ? e + 1 : em;
        int e2 = (e + 2 < end) ? e + 2 : em;
        int2 q0 = esw[e], q1 = esw[e1], q2 = esw[e2], q3 = esw[em];
        float w0 = __int_as_float(q0.y);
        float w1 = (e + 1 < end) ? __int_as_float(q1.y) : 0.f;
        float w2 = (e + 2 < end) ? __int_as_float(q2.y) : 0.f;
        float w3 = (e + 3 < end) ? __int_as_float(q3.y) : 0.f;
        float b0 = GTH(q0), b1 = GTH(q1), b2 = GTH(q2), b3 = GTH(q3);
        a0 += w0 * b0 + w1 * b1 + w2 * b2 + w3 * b3;
    }
#undef GTH
    outF[(size_t)wid * 64 + lane] = dd * a0 + bias[lane];
}

// ---------------- f16x3 MFMA GEMM ----------------
__device__ __forceinline__ void gl_lds16(const _Float16* g, _Float16* l) {
    __builtin_amdgcn_global_load_lds(
        (const __attribute__((address_space(1))) uint32_t*)g,
        (__attribute__((address_space(3))) uint32_t*)l, 16, 0, 0);
}

// Wide GEMM: out[n x 256] = A[n x FI] @ Wt^T (+bias, relu).
// BM=128, BN=256, BK=32, 256 threads (4 waves; wave w owns cols [w*64, w*64+64)).
// LDS 48KB: A_hi[0,4K) A_lo[4K,8K) B_hi[8K,16K) B_lo[16K,24K) (f16 indices).
// OUTMODE 0: packed (h,l) u32 out.  OUTMODE 1: hi/lo planes out.
template <int FI, int OUTMODE>
__global__ __launch_bounds__(256) void gemm_wide(
    const _Float16* __restrict__ Ah, const _Float16* __restrict__ Al,
    const _Float16* __restrict__ Wth, const _Float16* __restrict__ Wtl,  // [256][FI]
    const float* __restrict__ bias,
    uint32_t* __restrict__ Opk, _Float16* __restrict__ Oh, _Float16* __restrict__ Ol,
    int n) {
    constexpr int BK = 32;
    constexpr int NSTEP = FI / BK;
    constexpr int AHALF = 4096;   // f16 idx of A-lo plane
    constexpr int BH = 8192;      // f16 idx of B-hi
    constexpr int BL = 16384;     // f16 idx of B-lo
    __shared__ _Float16 lds[24576];
    const int m0 = blockIdx.x * 128;
    const int t = threadIdx.x;
    const int w = t >> 6;
    const int lane = t & 63;

    // A staging: thread handles granules t (rows 0..63) and t+256 (rows 64..127)
    const int r0 = w * 16 + (lane & 15);
    const int akc = (lane >> 4) * 8;
    const _Float16* sAh0 = Ah + (size_t)(m0 + r0) * FI + akc;
    const _Float16* sAh1 = Ah + (size_t)(m0 + r0 + 64) * FI + akc;
    const _Float16* sAl0 = Al + (size_t)(m0 + r0) * FI + akc;
    const _Float16* sAl1 = Al + (size_t)(m0 + r0 + 64) * FI + akc;
    // B staging: wave w stages col-subtiles w*4+q (16 cols x 32 k each)
    size_t boff[4];
    #pragma unroll
    for (int q = 0; q < 4; ++q)
        boff[q] = (size_t)((w * 4 + q) * 16 + (lane & 15)) * FI + akc;

    v4f acc[8][4];
    #pragma unroll
    for (int i = 0; i < 8; ++i)
        #pragma unroll
        for (int j = 0; j < 4; ++j) acc[i][j] = (v4f){0.f, 0.f, 0.f, 0.f};

    for (int s = 0; s < NSTEP; ++s) {
        const int ko = s * BK;
        gl_lds16(sAh0 + ko, &lds[w * 512]);
        gl_lds16(sAh1 + ko, &lds[2048 + w * 512]);
        gl_lds16(sAl0 + ko, &lds[AHALF + w * 512]);
        gl_lds16(sAl1 + ko, &lds[AHALF + 2048 + w * 512]);
        #pragma unroll
        for (int q = 0; q < 4; ++q) {
            gl_lds16(Wth + boff[q] + ko, &lds[BH + (w * 4 + q) * 512]);
            gl_lds16(Wtl + boff[q] + ko, &lds[BL + (w * 4 + q) * 512]);
        }
        __syncthreads();  // drains vmcnt -> tile resident
        v8h bhf[4], blf[4];
        #pragma unroll
        for (int j = 0; j < 4; ++j) {
            bhf[j] = *(const v8h*)&lds[BH + (w * 4 + j) * 512 + lane * 8];
            blf[j] = *(const v8h*)&lds[BL + (w * 4 + j) * 512 + lane * 8];
        }
        #pragma unroll
        for (int i = 0; i < 8; ++i) {
            v8h ahf = *(const v8h*)&lds[i * 512 + lane * 8];
            v8h alf = *(const v8h*)&lds[AHALF + i * 512 + lane * 8];
            #pragma unroll
            for (int j = 0; j < 4; ++j) {
                acc[i][j] = __builtin_amdgcn_mfma_f32_16x16x32_f16(ahf, bhf[j], acc[i][j], 0, 0, 0);
                acc[i][j] = __builtin_amdgcn_mfma_f32_16x16x32_f16(ahf, blf[j], acc[i][j], 0, 0, 0);
                acc[i][j] = __builtin_amdgcn_mfma_f32_16x16x32_f16(alf, bhf[j], acc[i][j], 0, 0, 0);
            }
        }
        __syncthreads();  // compute done before next overwrite
    }

    const int rl = (lane >> 4) * 4;
    const int cl = lane & 15;
    #pragma unroll
    for (int j = 0; j < 4; ++j) {
        const int gcol = w * 64 + j * 16 + cl;
        const float bv = bias[gcol];
        #pragma unroll
        for (int i = 0; i < 8; ++i) {
            const int grow = m0 + i * 16 + rl;
            #pragma unroll
            for (int r = 0; r < 4; ++r) {
                if (grow + r < n) {
                    float v = fmaxf(acc[i][j][r] + bv, 0.f);
                    _Float16 h = (_Float16)v;
                    _Float16 l = (_Float16)(v - (float)h);
                    if (OUTMODE == 0) {
                        uint32_t u = (uint32_t)__builtin_bit_cast(uint16_t, h) |
                                     ((uint32_t)__builtin_bit_cast(uint16_t, l) << 16);
                        Opk[(size_t)(grow + r) * 256 + gcol] = u;
                    } else {
                        Oh[(size_t)(grow + r) * 256 + gcol] = h;
                        Ol[(size_t)(grow + r) * 256 + gcol] = l;
                    }
                }
            }
        }
    }
}

// Narrow GEMM for L5: out[n x 64] f32 = A[n x 256] @ Wt^T, no bias/relu.
__global__ __launch_bounds__(256) void gemm_narrow(
    const _Float16* __restrict__ Ah, const _Float16* __restrict__ Al,
    const _Float16* __restrict__ Wth, const _Float16* __restrict__ Wtl,  // [64][256]
    float* __restrict__ Of, int n) {
    constexpr int FI = 256, FO = 64;
    __shared__ _Float16 lds[12288];
    const int m0 = blockIdx.x * 128;
    const int t = threadIdx.x;
    const int w = t >> 6;
    const int lane = t & 63;

    const int G0 = w * 128 + lane;
    const int G1 = G0 + 64;
    const int arow0 = (G0 >> 6) * 16 + (G0 & 15), akc0 = ((G0 >> 4) & 3) * 8;
    const int arow1 = (G1 >> 6) * 16 + (G1 & 15), akc1 = ((G1 >> 4) & 3) * 8;
    const _Float16* sAh0 = Ah + (size_t)(m0 + arow0) * FI + akc0;
    const _Float16* sAh1 = Ah + (size_t)(m0 + arow1) * FI + akc1;
    const _Float16* sAl0 = Al + (size_t)(m0 + arow0) * FI + akc0;
    const _Float16* sAl1 = Al + (size_t)(m0 + arow1) * FI + akc1;
    const int bcol = w * 16 + (lane & 15), bkc = (lane >> 4) * 8;
    const _Float16* sBh = Wth + (size_t)bcol * FI + bkc;
    const _Float16* sBl = Wtl + (size_t)bcol * FI + bkc;

    _Float16* dAh0 = &lds[w * 1024];
    _Float16* dAh1 = &lds[w * 1024 + 512];
    _Float16* dAl0 = &lds[4096 + w * 1024];
    _Float16* dAl1 = &lds[4096 + w * 1024 + 512];
    _Float16* dBh = &lds[8192 + w * 512];
    _Float16* dBl = &lds[10240 + w * 512];

    const int wm = w >> 1, wn = w & 1;
    v4f acc[4][2];
    #pragma unroll
    for (int i = 0; i < 4; ++i)
        #pragma unroll
        for (int j = 0; j < 2; ++j) acc[i][j] = (v4f){0.f, 0.f, 0.f, 0.f};

    for (int s = 0; s < 8; ++s) {
        const int ko = s * 32;
        gl_lds16(sAh0 + ko, dAh0);
        gl_lds16(sAh1 + ko, dAh1);
        gl_lds16(sAl0 + ko, dAl0);
        gl_lds16(sAl1 + ko, dAl1);
        gl_lds16(sBh + ko, dBh);
        gl_lds16(sBl + ko, dBl);
        __syncthreads();
        v8h ah[4], al[4], bh[2], bl[2];
        #pragma unroll
        for (int i = 0; i < 4; ++i) {
            ah[i] = *(const v8h*)&lds[(wm * 4 + i) * 512 + lane * 8];
            al[i] = *(const v8h*)&lds[4096 + (wm * 4 + i) * 512 + lane * 8];
        }
        #pragma unroll
        for (int j = 0; j < 2; ++j) {
            bh[j] = *(const v8h*)&lds[8192 + (wn * 2 + j) * 512 + lane * 8];
            bl[j] = *(const v8h*)&lds[10240 + (wn * 2 + j) * 512 + lane * 8];
        }
        #pragma unroll
        for (int i = 0; i < 4; ++i)
            #pragma unroll
            for (int j = 0; j < 2; ++j) {
                acc[i][j] = __builtin_amdgcn_mfma_f32_16x16x32_f16(ah[i], bh[j], acc[i][j], 0, 0, 0);
                acc[i][j] = __builtin_amdgcn_mfma_f32_16x16x32_f16(ah[i], bl[j], acc[i][j], 0, 0, 0);
                acc[i][j] = __builtin_amdgcn_mfma_f32_16x16x32_f16(al[i], bh[j], acc[i][j], 0, 0, 0);
            }
        __syncthreads();
    }

    const int rl = (lane >> 4) * 4;
    const int cl = lane & 15;
    #pragma unroll
    for (int j = 0; j < 2; ++j) {
        const int gcol = wn * 32 + j * 16 + cl;
        #pragma unroll
        for (int i = 0; i < 4; ++i) {
            const int grow = m0 + wm * 64 + i * 16 + rl;
            #pragma unroll
            for (int r = 0; r < 4; ++r)
                if (grow + r < n) Of[(size_t)(grow + r) * FO + gcol] = acc[i][j][r];
        }
    }
}

// ---------------- launcher ----------------
extern "C" void kernel_launch(void* const* d_in, const int* in_sizes, int n_in,
                              void* d_out, int out_size, void* d_ws, size_t ws_size,
                              hipStream_t stream) {
    const float* x = (const float*)d_in[0];
    const int* ei = (const int*)d_in[1];
    const int E = in_sizes[1] / 2;
    const int n = in_sizes[0] / 128;
    const int* esrc = ei;
    const int* edst = ei + E;
    const float* b[5] = {(const float*)d_in[3], (const float*)d_in[5], (const float*)d_in[7],
                         (const float*)d_in[9], (const float*)d_in[11]};
    float* out = (float*)d_out;
    const int NPAD = ((n + 127) / 128) * 128;

    char* ws = (char*)d_ws;
    auto carve = [&](size_t bytes) {
        char* p = ws;
        ws += (bytes + 255) & ~(size_t)255;
        return p;
    };
    int* counts = (int*)carve((size_t)n * 4);
    int* row_ptr = (int*)carve((size_t)(n + 1) * 4);
    int* fill = (int*)carve((size_t)n * 4);
    float* dinv = (float*)carve((size_t)n * 4);
    int* partial = (int*)carve(1024);
    int2* esw = (int2*)carve((size_t)E * 8);
    const int FIs[5] = {128, 256, 256, 256, 256};
    const int FOs[5] = {256, 256, 256, 256, 64};
    _Float16 *Wh[5], *Wl[5];
    for (int l = 0; l < 5; ++l) {
        Wh[l] = (_Float16*)carve((size_t)FIs[l] * FOs[l] * 2);
        Wl[l] = (_Float16*)carve((size_t)FIs[l] * FOs[l] * 2);
    }
    _Float16* Ah = (_Float16*)carve((size_t)NPAD * 256 * 2);
    _Float16* Al = (_Float16*)carve((size_t)NPAD * 256 * 2);
    uint32_t* Ppk = (uint32_t*)carve((size_t)NPAD * 256 * 4);
    _Float16* Bh2 = (_Float16*)Ppk;                    // L4 planes out (aliases Ppk)
    _Float16* Bl2 = (_Float16*)Ppk + (size_t)NPAD * 256;
    float* scratch = (float*)Ah;                       // L5 gemm f32 out (n x 64)

    hipMemsetAsync(counts, 0, (size_t)n * 4, stream);
    count_edges<<<(E + 255) / 256, 256, 0, stream>>>(edst, E, counts);
    const int nsb = (n + 255) / 256;
    block_sums<<<nsb, 256, 0, stream>>>(counts, n, partial);
    scan_partials<<<1, 256, 0, stream>>>(partial, nsb, row_ptr, n);
    scan_final<<<nsb, 256, 0, stream>>>(counts, n, partial, row_ptr, dinv, fill);
    build_csr<<<(E + 255) / 256, 256, 0, stream>>>(esrc, edst, E, row_ptr, fill, esw, dinv);

    SplitArgs sa;
    int off = 0;
    for (int l = 0; l < 5; ++l) {
        sa.W[l] = (const float*)d_in[2 + 2 * l];
        sa.Wh[l] = Wh[l];
        sa.Wl[l] = Wl[l];
        sa.lgFI[l] = (FIs[l] == 128) ? 7 : 8;
        sa.FO[l] = FOs[l];
        sa.off[l] = off;
        off += FIs[l] * FOs[l];
    }
    sa.off[5] = off;
    split_all<<<(off + 255) / 256, 256, 0, stream>>>(sa);

    const int aggBlocks = (n + 3) / 4;
    const int gw = NPAD / 128;  // gemm_wide grid (BM=128)
    const int gn = NPAD / 128;  // gemm_narrow grid

    // L1
    agg_f32_128<<<aggBlocks, 256, 0, stream>>>(x, row_ptr, esw, dinv, Ah, Al, n);
    gemm_wide<128, 0><<<gw, 256, 0, stream>>>(Ah, Al, Wh[0], Wl[0], b[0], Ppk, nullptr, nullptr, n);
    // L2, L3
    for (int l = 1; l <= 2; ++l) {
        agg_packed<<<aggBlocks, 256, 0, stream>>>((const _Float16*)Ppk, row_ptr, esw, dinv, Ah, Al, n);
        gemm_wide<256, 0><<<gw, 256, 0, stream>>>(Ah, Al, Wh[l], Wl[l], b[l], Ppk, nullptr, nullptr, n);
    }
    // L4 -> planes
    agg_packed<<<aggBlocks, 256, 0, stream>>>((const _Float16*)Ppk, row_ptr, esw, dinv, Ah, Al, n);
    gemm_wide<256, 1><<<gw, 256, 0, stream>>>(Ah, Al, Wh[3], Wl[3], b[3], nullptr, Bh2, Bl2, n);
    // L5
    gemm_narrow<<<gn, 256, 0, stream>>>(Bh2, Bl2, Wh[4], Wl[4], scratch, n);
    agg_f32_64<<<(n + 3) / 4, 256, 0, stream>>>(scratch, row_ptr, esw, dinv, b[4], out, n);
}

// Round 8
// 668.977 us; speedup vs baseline: 1.1097x; 1.1097x over previous
//
#include <hip/hip_runtime.h>
#include <stdint.h>

// ---------------------------------------------------------------------------
// GCN 5-layer, N=50000, E=600000.  out = ((Anorm @ h) @ W) + b per layer.
// Activations: f16 hi/lo (22-bit mantissa). Packed (h,l) pairs for the agg
// gather (request-BW-bound ~6.9 TB/s demand = ceiling); hi/lo planes for GEMM.
// R6 lesson: no agg+GEMM fusion (occupancy). R7 lesson: BM=64 beats BM=128.
// GEMM = f16x3 split MFMA with 32x32x16 fragments (24 MFMA/K-step, was 48).
// ---------------------------------------------------------------------------

typedef _Float16 v8h __attribute__((ext_vector_type(8)));
typedef _Float16 v4h __attribute__((ext_vector_type(4)));
typedef _Float16 v2h __attribute__((ext_vector_type(2)));
typedef float v4f __attribute__((ext_vector_type(4)));
typedef float v16f __attribute__((ext_vector_type(16)));

// ---------------- CSR build ----------------
__global__ void count_edges(const int* __restrict__ dst, int E, int* __restrict__ counts) {
    int i = blockIdx.x * blockDim.x + threadIdx.x;
    if (i < E) atomicAdd(&counts[dst[i]], 1);
}

__global__ void block_sums(const int* __restrict__ counts, int n, int* __restrict__ partial) {
    __shared__ int red[256];
    int t = threadIdx.x;
    int i = blockIdx.x * 256 + t;
    red[t] = (i < n) ? counts[i] : 0;
    __syncthreads();
    #pragma unroll
    for (int off = 128; off > 0; off >>= 1) {
        if (t < off) red[t] += red[t + off];
        __syncthreads();
    }
    if (t == 0) partial[blockIdx.x] = red[0];
}

__global__ void scan_partials(int* __restrict__ partial, int nb, int* __restrict__ row_ptr, int n) {
    __shared__ int s[256];
    int t = threadIdx.x;
    int v = (t < nb) ? partial[t] : 0;
    s[t] = v;
    __syncthreads();
    #pragma unroll
    for (int off = 1; off < 256; off <<= 1) {
        int u = (t >= off) ? s[t - off] : 0;
        __syncthreads();
        s[t] += u;
        __syncthreads();
    }
    if (t < nb) partial[t] = s[t] - v;
    if (t == 0) row_ptr[n] = s[255];
}

__global__ void scan_final(const int* __restrict__ counts, int n, const int* __restrict__ partial,
                           int* __restrict__ row_ptr, float* __restrict__ dinv,
                           int* __restrict__ fill) {
    __shared__ int s[256];
    int t = threadIdx.x;
    int i = blockIdx.x * 256 + t;
    int c = (i < n) ? counts[i] : 0;
    s[t] = c;
    __syncthreads();
    #pragma unroll
    for (int off = 1; off < 256; off <<= 1) {
        int u = (t >= off) ? s[t - off] : 0;
        __syncthreads();
        s[t] += u;
        __syncthreads();
    }
    if (i < n) {
        row_ptr[i] = partial[blockIdx.x] + s[t] - c;
        dinv[i] = rsqrtf((float)(c + 1));
        fill[i] = 0;
    }
}

__global__ void build_csr(const int* __restrict__ src, const int* __restrict__ dst, int E,
                          const int* __restrict__ row_ptr, int* __restrict__ fill,
                          int2* __restrict__ esw, const float* __restrict__ dinv) {
    int i = blockIdx.x * blockDim.x + threadIdx.x;
    if (i < E) {
        int d = dst[i];
        int s = src[i];
        int pos = row_ptr[d] + atomicAdd(&fill[d], 1);
        esw[pos] = make_int2(s, __float_as_int(dinv[s]));
    }
}

// ---------------- weight split+transpose (all 5 layers, one launch) ----------------
struct SplitArgs {
    const float* W[5];
    _Float16* Wh[5];
    _Float16* Wl[5];
    int lgFI[5];
    int FO[5];
    int off[6];
};

__global__ void split_all(SplitArgs a) {
    int i = blockIdx.x * 256 + threadIdx.x;
    #pragma unroll
    for (int l = 0; l < 5; ++l) {
        if (i >= a.off[l] && i < a.off[l + 1]) {
            int j = i - a.off[l];
            int FI = 1 << a.lgFI[l];
            int c = j >> a.lgFI[l];
            int k = j & (FI - 1);
            float v = a.W[l][(size_t)k * a.FO[l] + c];
            _Float16 h = (_Float16)v;
            a.Wh[l][j] = h;
            a.Wl[l][j] = (_Float16)(v - (float)h);
        }
    }
}

// ---------------- aggregation: packed-in (L2..L4), F=256 ----------------
__global__ __launch_bounds__(256) void agg_packed(
    const _Float16* __restrict__ inP, const int* __restrict__ row_ptr,
    const int2* __restrict__ esw, const float* __restrict__ dinv,
    _Float16* __restrict__ outH, _Float16* __restrict__ outL, int n) {
    int wid = (blockIdx.x * blockDim.x + threadIdx.x) >> 6;
    if (wid >= n) return;
    const int lane = threadIdx.x & 63;
    int e = __builtin_amdgcn_readfirstlane(row_ptr[wid]);
    const int end = __builtin_amdgcn_readfirstlane(row_ptr[wid + 1]);
    const float dd = dinv[wid];
    const _Float16* rb = inP + (size_t)lane * 8;
    float a0, a1, a2, a3;
    {
        v8h p = *(const v8h*)(rb + (size_t)wid * 512);
        a0 = dd * ((float)p[0] + (float)p[1]);
        a1 = dd * ((float)p[2] + (float)p[3]);
        a2 = dd * ((float)p[4] + (float)p[5]);
        a3 = dd * ((float)p[6] + (float)p[7]);
    }
#define GTH(q) (*(const v8h*)(rb + (size_t)(q).x * 512))
#define ACC(b, w)                                  \
    a0 += (w) * ((float)(b)[0] + (float)(b)[1]);   \
    a1 += (w) * ((float)(b)[2] + (float)(b)[3]);   \
    a2 += (w) * ((float)(b)[4] + (float)(b)[5]);   \
    a3 += (w) * ((float)(b)[6] + (float)(b)[7]);
    for (; e + 8 <= end; e += 8) {
        int2 q0 = esw[e + 0], q1 = esw[e + 1], q2 = esw[e + 2], q3 = esw[e + 3];
        int2 q4 = esw[e + 4], q5 = esw[e + 5], q6 = esw[e + 6], q7 = esw[e + 7];
        v8h b0 = GTH(q0), b1 = GTH(q1), b2 = GTH(q2), b3 = GTH(q3);
        v8h b4 = GTH(q4), b5 = GTH(q5), b6 = GTH(q6), b7 = GTH(q7);
        ACC(b0, __int_as_float(q0.y)) ACC(b1, __int_as_float(q1.y))
        ACC(b2, __int_as_float(q2.y)) ACC(b3, __int_as_float(q3.y))
        ACC(b4, __int_as_float(q4.y)) ACC(b5, __int_as_float(q5.y))
        ACC(b6, __int_as_float(q6.y)) ACC(b7, __int_as_float(q7.y))
    }
    if (e + 4 <= end) {
        int2 q0 = esw[e + 0], q1 = esw[e + 1], q2 = esw[e + 2], q3 = esw[e + 3];
        v8h b0 = GTH(q0), b1 = GTH(q1), b2 = GTH(q2), b3 = GTH(q3);
        ACC(b0, __int_as_float(q0.y)) ACC(b1, __int_as_float(q1.y))
        ACC(b2, __int_as_float(q2.y)) ACC(b3, __int_as_float(q3.y))
        e += 4;
    }
    if (e < end) {
        const int em = end - 1;
        int e1 = (e + 1 < end) ? e + 1 : em;
        int e2 = (e + 2 < end) ? e + 2 : em;
        int2 q0 = esw[e], q1 = esw[e1], q2 = esw[e2], q3 = esw[em];
        float w0 = __int_as_float(q0.y);
        float w1 = (e + 1 < end) ? __int_as_float(q1.y) : 0.f;
        float w2 = (e + 2 < end) ? __int_as_float(q2.y) : 0.f;
        float w3 = (e + 3 < end) ? __int_as_float(q3.y) : 0.f;
        v8h b0 = GTH(q0), b1 = GTH(q1), b2 = GTH(q2), b3 = GTH(q3);
        ACC(b0, w0) ACC(b1, w1) ACC(b2, w2) ACC(b3, w3)
    }
#undef GTH
#undef ACC
    size_t o = (size_t)wid * 256 + lane * 4;
    float s0 = dd * a0, s1 = dd * a1, s2 = dd * a2, s3 = dd * a3;
    _Float16 h0 = (_Float16)s0, h1 = (_Float16)s1, h2 = (_Float16)s2, h3 = (_Float16)s3;
    *(v4h*)&outH[o] = (v4h){h0, h1, h2, h3};
    *(v4h*)&outL[o] = (v4h){(_Float16)(s0 - (float)h0), (_Float16)(s1 - (float)h1),
                            (_Float16)(s2 - (float)h2), (_Float16)(s3 - (float)h3)};
}

// ---------------- aggregation: f32-in 128 feats (L1) -> hi/lo planes ----------------
__global__ __launch_bounds__(256) void agg_f32_128(
    const float* __restrict__ in, const int* __restrict__ row_ptr,
    const int2* __restrict__ esw, const float* __restrict__ dinv,
    _Float16* __restrict__ outH, _Float16* __restrict__ outL, int n) {
    int wid = (blockIdx.x * blockDim.x + threadIdx.x) >> 6;
    if (wid >= n) return;
    const int lane = threadIdx.x & 63;
    int e = __builtin_amdgcn_readfirstlane(row_ptr[wid]);
    const int end = __builtin_amdgcn_readfirstlane(row_ptr[wid + 1]);
    const float dd = dinv[wid];
    const float* rb = in + (size_t)lane * 2;
    float a0, a1;
    {
        float2 p = *(const float2*)(rb + (size_t)wid * 128);
        a0 = dd * p.x;
        a1 = dd * p.y;
    }
#define GTH(q) (*(const float2*)(rb + (size_t)(q).x * 128))
#define ACC(b, w) a0 += (w) * (b).x; a1 += (w) * (b).y;
    for (; e + 8 <= end; e += 8) {
        int2 q0 = esw[e + 0], q1 = esw[e + 1], q2 = esw[e + 2], q3 = esw[e + 3];
        int2 q4 = esw[e + 4], q5 = esw[e + 5], q6 = esw[e + 6], q7 = esw[e + 7];
        float2 b0 = GTH(q0), b1 = GTH(q1), b2 = GTH(q2), b3 = GTH(q3);
        float2 b4 = GTH(q4), b5 = GTH(q5), b6 = GTH(q6), b7 = GTH(q7);
        ACC(b0, __int_as_float(q0.y)) ACC(b1, __int_as_float(q1.y))
        ACC(b2, __int_as_float(q2.y)) ACC(b3, __int_as_float(q3.y))
        ACC(b4, __int_as_float(q4.y)) ACC(b5, __int_as_float(q5.y))
        ACC(b6, __int_as_float(q6.y)) ACC(b7, __int_as_float(q7.y))
    }
    if (e + 4 <= end) {
        int2 q0 = esw[e + 0], q1 = esw[e + 1], q2 = esw[e + 2], q3 = esw[e + 3];
        float2 b0 = GTH(q0), b1 = GTH(q1), b2 = GTH(q2), b3 = GTH(q3);
        ACC(b0, __int_as_float(q0.y)) ACC(b1, __int_as_float(q1.y))
        ACC(b2, __int_as_float(q2.y)) ACC(b3, __int_as_float(q3.y))
        e += 4;
    }
    if (e < end) {
        const int em = end - 1;
        int e1 = (e + 1 < end) ? e + 1 : em;
        int e2 = (e + 2 < end) ? e + 2 : em;
        int2 q0 = esw[e], q1 = esw[e1], q2 = esw[e2], q3 = esw[em];
        float w0 = __int_as_float(q0.y);
        float w1 = (e + 1 < end) ? __int_as_float(q1.y) : 0.f;
        float w2 = (e + 2 < end) ? __int_as_float(q2.y) : 0.f;
        float w3 = (e + 3 < end) ? __int_as_float(q3.y) : 0.f;
        float2 b0 = GTH(q0), b1 = GTH(q1), b2 = GTH(q2), b3 = GTH(q3);
        ACC(b0, w0) ACC(b1, w1) ACC(b2, w2) ACC(b3, w3)
    }
#undef GTH
#undef ACC
    size_t o = (size_t)wid * 128 + lane * 2;
    float s0 = dd * a0, s1 = dd * a1;
    _Float16 h0 = (_Float16)s0, h1 = (_Float16)s1;
    *(v2h*)&outH[o] = (v2h){h0, h1};
    *(v2h*)&outL[o] = (v2h){(_Float16)(s0 - (float)h0), (_Float16)(s1 - (float)h1)};
}

// ---------------- aggregation: f32-in 64 feats (L5) -> f32 + bias ----------------
__global__ __launch_bounds__(256) void agg_f32_64(
    const float* __restrict__ in, const int* __restrict__ row_ptr,
    const int2* __restrict__ esw, const float* __restrict__ dinv,
    const float* __restrict__ bias, float* __restrict__ outF, int n) {
    int wid = (blockIdx.x * blockDim.x + threadIdx.x) >> 6;
    if (wid >= n) return;
    const int lane = threadIdx.x & 63;
    int e = __builtin_amdgcn_readfirstlane(row_ptr[wid]);
    const int end = __builtin_amdgcn_readfirstlane(row_ptr[wid + 1]);
    const float dd = dinv[wid];
    const float* rb = in + lane;
    float a0 = dd * rb[(size_t)wid * 64];
#define GTH(q) (rb[(size_t)(q).x * 64])
    for (; e + 8 <= end; e += 8) {
        int2 q0 = esw[e + 0], q1 = esw[e + 1], q2 = esw[e + 2], q3 = esw[e + 3];
        int2 q4 = esw[e + 4], q5 = esw[e + 5], q6 = esw[e + 6], q7 = esw[e + 7];
        float b0 = GTH(q0), b1 = GTH(q1), b2 = GTH(q2), b3 = GTH(q3);
        float b4 = GTH(q4), b5 = GTH(q5), b6 = GTH(q6), b7 = GTH(q7);
        a0 += __int_as_float(q0.y) * b0 + __int_as_float(q1.y) * b1;
        a0 += __int_as_float(q2.y) * b2 + __int_as_float(q3.y) * b3;
        a0 += __int_as_float(q4.y) * b4 + __int_as_float(q5.y) * b5;
        a0 += __int_as_float(q6.y) * b6 + __int_as_float(q7.y) * b7;
    }
    if (e + 4 <= end) {
        int2 q0 = esw[e + 0], q1 = esw[e + 1], q2 = esw[e + 2], q3 = esw[e + 3];
        float b0 = GTH(q0), b1 = GTH(q1), b2 = GTH(q2), b3 = GTH(q3);
        a0 += __int_as_float(q0.y) * b0 + __int_as_float(q1.y) * b1;
        a0 += __int_as_float(q2.y) * b2 + __int_as_float(q3.y) * b3;
        e += 4;
    }
    if (e < end) {
        const int em = end - 1;
        int e1 = (e + 1 < end) ? e + 1 : em;
        int e2 = (e + 2 < end) ? e + 2 : em;
        int2 q0 = esw[e], q1 = esw[e1], q2 = esw[e2], q3 = esw[em];
        float w0 = __int_as_float(q0.y);
        float w1 = (e + 1 < end) ? __int_as_float(q1.y) : 0.f;
        float w2 = (e + 2 < end) ? __int_as_float(q2.y) : 0.f;
        float w3 = (e + 3 < end) ? __int_as_float(q3.y) : 0.f;
        float b0 = GTH(q0), b1 = GTH(q1), b2 = GTH(q2), b3 = GTH(q3);
        a0 += w0 * b0 + w1 * b1 + w2 * b2 + w3 * b3;
    }
#undef GTH
    outF[(size_t)wid * 64 + lane] = dd * a0 + bias[lane];
}

// ---------------- f16x3 MFMA GEMM ----------------
__device__ __forceinline__ void gl_lds16(const _Float16* g, _Float16* l) {
    __builtin_amdgcn_global_load_lds(
        (const __attribute__((address_space(1))) uint32_t*)g,
        (__attribute__((address_space(3))) uint32_t*)l, 16, 0, 0);
}

// Wide GEMM: out[n x 256] = A[n x FI] @ Wt^T (+bias, relu).  BM=64, BN=256,
// BK=32, 4 waves (wave w owns cols [w*64, w*64+64)), 32x32x16 fragments.
// LDS (f16 idx): A_hi[0,2048) A_lo[2048,4096) B_hi[4096,12288) B_lo[12288,20480)
// Granule layout (16 rows x 32 k per 512-f16 block): off = kchunk*128 + row*8.
// OUTMODE 0: packed (h,l) u32 out.  OUTMODE 1: hi/lo planes out.
template <int FI, int OUTMODE>
__global__ __launch_bounds__(256) void gemm_wide(
    const _Float16* __restrict__ Ah, const _Float16* __restrict__ Al,
    const _Float16* __restrict__ Wth, const _Float16* __restrict__ Wtl,  // [256][FI]
    const float* __restrict__ bias,
    uint32_t* __restrict__ Opk, _Float16* __restrict__ Oh, _Float16* __restrict__ Ol,
    int n) {
    constexpr int BK = 32;
    constexpr int NSTEP = FI / BK;
    __shared__ _Float16 lds[20480];
    const int m0 = blockIdx.x * 64;
    const int t = threadIdx.x;
    const int w = t >> 6;
    const int lane = t & 63;

    // A staging (identical to the verified 16x16 version): thread stages row
    // w*16+(lane&15), k-chunk (lane>>4)*8 -> LDS block w*512, lane-linear.
    const int arow = w * 16 + (lane & 15);
    const int akc = (lane >> 4) * 8;
    const _Float16* sAh = Ah + (size_t)(m0 + arow) * FI + akc;
    const _Float16* sAl = Al + (size_t)(m0 + arow) * FI + akc;
    _Float16* dAh = &lds[w * 512];
    _Float16* dAl = &lds[2048 + w * 512];
    // B staging: wave w stages col-subtiles w*4+q (16 cols x 32 k each).
    size_t boff[4];
    #pragma unroll
    for (int q = 0; q < 4; ++q)
        boff[q] = (size_t)((w * 4 + q) * 16 + (lane & 15)) * FI + akc;

    v16f acc[2][2];
    #pragma unroll
    for (int i = 0; i < 2; ++i)
        #pragma unroll
        for (int j = 0; j < 2; ++j) acc[i][j] = (v16f)(0.f);

    // 32x32x16 fragment addressing within granules:
    const int rsel = (lane >> 4) & 1;  // which 16-row/col granule of the 32-block
    const int kq = lane >> 5;          // k sub-chunk of 8 within the K=16 half
    const int l8 = (lane & 15) * 8;

    for (int s = 0; s < NSTEP; ++s) {
        const int ko = s * BK;
        gl_lds16(sAh + ko, dAh);
        gl_lds16(sAl + ko, dAl);
        #pragma unroll
        for (int q = 0; q < 4; ++q) {
            gl_lds16(Wth + boff[q] + ko, &lds[4096 + (w * 4 + q) * 512]);
            gl_lds16(Wtl + boff[q] + ko, &lds[12288 + (w * 4 + q) * 512]);
        }
        __syncthreads();  // drains vmcnt -> tile resident
        v8h ah[2][2], al[2][2], bh[2][2], bl[2][2];
        #pragma unroll
        for (int i = 0; i < 2; ++i)
            #pragma unroll
            for (int ks = 0; ks < 2; ++ks) {
                const int aoff = (i * 2 + rsel) * 512 + (ks * 2 + kq) * 128 + l8;
                ah[i][ks] = *(const v8h*)&lds[aoff];
                al[i][ks] = *(const v8h*)&lds[2048 + aoff];
            }
        #pragma unroll
        for (int j = 0; j < 2; ++j)
            #pragma unroll
            for (int ks = 0; ks < 2; ++ks) {
                const int bo = 4096 + (w * 4 + j * 2 + rsel) * 512 + (ks * 2 + kq) * 128 + l8;
                bh[j][ks] = *(const v8h*)&lds[bo];
                bl[j][ks] = *(const v8h*)&lds[bo + 8192];
            }
        #pragma unroll
        for (int i = 0; i < 2; ++i)
            #pragma unroll
            for (int j = 0; j < 2; ++j)
                #pragma unroll
                for (int ks = 0; ks < 2; ++ks) {
                    acc[i][j] = __builtin_amdgcn_mfma_f32_32x32x16_f16(ah[i][ks], bh[j][ks], acc[i][j], 0, 0, 0);
                    acc[i][j] = __builtin_amdgcn_mfma_f32_32x32x16_f16(ah[i][ks], bl[j][ks], acc[i][j], 0, 0, 0);
                    acc[i][j] = __builtin_amdgcn_mfma_f32_32x32x16_f16(al[i][ks], bh[j][ks], acc[i][j], 0, 0, 0);
                }
        __syncthreads();  // compute done before next overwrite
    }

    // C/D layout (32x32): col = lane&31, row = (reg&3) + 8*(reg>>2) + 4*(lane>>5)
    const int col = lane & 31;
    const int rb4 = (lane >> 5) * 4;
    #pragma unroll
    for (int j = 0; j < 2; ++j) {
        const int gcol = w * 64 + j * 32 + col;
        const float bv = bias[gcol];
        #pragma unroll
        for (int i = 0; i < 2; ++i) {
            #pragma unroll
            for (int reg = 0; reg < 16; ++reg) {
                const int row = (reg & 3) + 8 * (reg >> 2) + rb4;
                const int grow = m0 + i * 32 + row;
                if (grow < n) {
                    float v = fmaxf(acc[i][j][reg] + bv, 0.f);
                    _Float16 h = (_Float16)v;
                    _Float16 l = (_Float16)(v - (float)h);
                    if (OUTMODE == 0) {
                        uint32_t u = (uint32_t)__builtin_bit_cast(uint16_t, h) |
                                     ((uint32_t)__builtin_bit_cast(uint16_t, l) << 16);
                        Opk[(size_t)grow * 256 + gcol] = u;
                    } else {
                        Oh[(size_t)grow * 256 + gcol] = h;
                        Ol[(size_t)grow * 256 + gcol] = l;
                    }
                }
            }
        }
    }
}

// Narrow GEMM for L5: out[n x 64] f32 = A[n x 256] @ Wt^T, no bias/relu.
__global__ __launch_bounds__(256) void gemm_narrow(
    const _Float16* __restrict__ Ah, const _Float16* __restrict__ Al,
    const _Float16* __restrict__ Wth, const _Float16* __restrict__ Wtl,  // [64][256]
    float* __restrict__ Of, int n) {
    constexpr int FI = 256, FO = 64;
    __shared__ _Float16 lds[12288];
    const int m0 = blockIdx.x * 128;
    const int t = threadIdx.x;
    const int w = t >> 6;
    const int lane = t & 63;

    const int G0 = w * 128 + lane;
    const int G1 = G0 + 64;
    const int arow0 = (G0 >> 6) * 16 + (G0 & 15), akc0 = ((G0 >> 4) & 3) * 8;
    const int arow1 = (G1 >> 6) * 16 + (G1 & 15), akc1 = ((G1 >> 4) & 3) * 8;
    const _Float16* sAh0 = Ah + (size_t)(m0 + arow0) * FI + akc0;
    const _Float16* sAh1 = Ah + (size_t)(m0 + arow1) * FI + akc1;
    const _Float16* sAl0 = Al + (size_t)(m0 + arow0) * FI + akc0;
    const _Float16* sAl1 = Al + (size_t)(m0 + arow1) * FI + akc1;
    const int bcol = w * 16 + (lane & 15), bkc = (lane >> 4) * 8;
    const _Float16* sBh = Wth + (size_t)bcol * FI + bkc;
    const _Float16* sBl = Wtl + (size_t)bcol * FI + bkc;

    _Float16* dAh0 = &lds[w * 1024];
    _Float16* dAh1 = &lds[w * 1024 + 512];
    _Float16* dAl0 = &lds[4096 + w * 1024];
    _Float16* dAl1 = &lds[4096 + w * 1024 + 512];
    _Float16* dBh = &lds[8192 + w * 512];
    _Float16* dBl = &lds[10240 + w * 512];

    const int wm = w >> 1, wn = w & 1;
    v4f acc[4][2];
    #pragma unroll
    for (int i = 0; i < 4; ++i)
        #pragma unroll
        for (int j = 0; j < 2; ++j) acc[i][j] = (v4f){0.f, 0.f, 0.f, 0.f};

    for (int s = 0; s < 8; ++s) {
        const int ko = s * 32;
        gl_lds16(sAh0 + ko, dAh0);
        gl_lds16(sAh1 + ko, dAh1);
        gl_lds16(sAl0 + ko, dAl0);
        gl_lds16(sAl1 + ko, dAl1);
        gl_lds16(sBh + ko, dBh);
        gl_lds16(sBl + ko, dBl);
        __syncthreads();
        v8h ah[4], al[4], bh[2], bl[2];
        #pragma unroll
        for (int i = 0; i < 4; ++i) {
            ah[i] = *(const v8h*)&lds[(wm * 4 + i) * 512 + lane * 8];
            al[i] = *(const v8h*)&lds[4096 + (wm * 4 + i) * 512 + lane * 8];
        }
        #pragma unroll
        for (int j = 0; j < 2; ++j) {
            bh[j] = *(const v8h*)&lds[8192 + (wn * 2 + j) * 512 + lane * 8];
            bl[j] = *(const v8h*)&lds[10240 + (wn * 2 + j) * 512 + lane * 8];
        }
        #pragma unroll
        for (int i = 0; i < 4; ++i)
            #pragma unroll
            for (int j = 0; j < 2; ++j) {
                acc[i][j] = __builtin_amdgcn_mfma_f32_16x16x32_f16(ah[i], bh[j], acc[i][j], 0, 0, 0);
                acc[i][j] = __builtin_amdgcn_mfma_f32_16x16x32_f16(ah[i], bl[j], acc[i][j], 0, 0, 0);
                acc[i][j] = __builtin_amdgcn_mfma_f32_16x16x32_f16(al[i], bh[j], acc[i][j], 0, 0, 0);
            }
        __syncthreads();
    }

    const int rl = (lane >> 4) * 4;
    const int cl = lane & 15;
    #pragma unroll
    for (int j = 0; j < 2; ++j) {
        const int gcol = wn * 32 + j * 16 + cl;
        #pragma unroll
        for (int i = 0; i < 4; ++i) {
            const int grow = m0 + wm * 64 + i * 16 + rl;
            #pragma unroll
            for (int r = 0; r < 4; ++r)
                if (grow + r < n) Of[(size_t)(grow + r) * FO + gcol] = acc[i][j][r];
        }
    }
}

// ---------------- launcher ----------------
extern "C" void kernel_launch(void* const* d_in, const int* in_sizes, int n_in,
                              void* d_out, int out_size, void* d_ws, size_t ws_size,
                              hipStream_t stream) {
    const float* x = (const float*)d_in[0];
    const int* ei = (const int*)d_in[1];
    const int E = in_sizes[1] / 2;
    const int n = in_sizes[0] / 128;
    const int* esrc = ei;
    const int* edst = ei + E;
    const float* b[5] = {(const float*)d_in[3], (const float*)d_in[5], (const float*)d_in[7],
                         (const float*)d_in[9], (const float*)d_in[11]};
    float* out = (float*)d_out;
    const int NPAD = ((n + 127) / 128) * 128;

    char* ws = (char*)d_ws;
    auto carve = [&](size_t bytes) {
        char* p = ws;
        ws += (bytes + 255) & ~(size_t)255;
        return p;
    };
    int* counts = (int*)carve((size_t)n * 4);
    int* row_ptr = (int*)carve((size_t)(n + 1) * 4);
    int* fill = (int*)carve((size_t)n * 4);
    float* dinv = (float*)carve((size_t)n * 4);
    int* partial = (int*)carve(1024);
    int2* esw = (int2*)carve((size_t)E * 8);
    const int FIs[5] = {128, 256, 256, 256, 256};
    const int FOs[5] = {256, 256, 256, 256, 64};
    _Float16 *Wh[5], *Wl[5];
    for (int l = 0; l < 5; ++l) {
        Wh[l] = (_Float16*)carve((size_t)FIs[l] * FOs[l] * 2);
        Wl[l] = (_Float16*)carve((size_t)FIs[l] * FOs[l] * 2);
    }
    _Float16* Ah = (_Float16*)carve((size_t)NPAD * 256 * 2);
    _Float16* Al = (_Float16*)carve((size_t)NPAD * 256 * 2);
    uint32_t* Ppk = (uint32_t*)carve((size_t)NPAD * 256 * 4);
    _Float16* Bh2 = (_Float16*)Ppk;                    // L4 planes out (aliases Ppk)
    _Float16* Bl2 = (_Float16*)Ppk + (size_t)NPAD * 256;
    float* scratch = (float*)Ah;                       // L5 gemm f32 out (n x 64)

    hipMemsetAsync(counts, 0, (size_t)n * 4, stream);
    count_edges<<<(E + 255) / 256, 256, 0, stream>>>(edst, E, counts);
    const int nsb = (n + 255) / 256;
    block_sums<<<nsb, 256, 0, stream>>>(counts, n, partial);
    scan_partials<<<1, 256, 0, stream>>>(partial, nsb, row_ptr, n);
    scan_final<<<nsb, 256, 0, stream>>>(counts, n, partial, row_ptr, dinv, fill);
    build_csr<<<(E + 255) / 256, 256, 0, stream>>>(esrc, edst, E, row_ptr, fill, esw, dinv);

    SplitArgs sa;
    int off = 0;
    for (int l = 0; l < 5; ++l) {
        sa.W[l] = (const float*)d_in[2 + 2 * l];
        sa.Wh[l] = Wh[l];
        sa.Wl[l] = Wl[l];
        sa.lgFI[l] = (FIs[l] == 128) ? 7 : 8;
        sa.FO[l] = FOs[l];
        sa.off[l] = off;
        off += FIs[l] * FOs[l];
    }
    sa.off[5] = off;
    split_all<<<(off + 255) / 256, 256, 0, stream>>>(sa);

    const int aggBlocks = (n + 3) / 4;
    const int gw = NPAD / 64;   // gemm_wide grid (BM=64)
    const int gn = NPAD / 128;  // gemm_narrow grid

    // L1
    agg_f32_128<<<aggBlocks, 256, 0, stream>>>(x, row_ptr, esw, dinv, Ah, Al, n);
    gemm_wide<128, 0><<<gw, 256, 0, stream>>>(Ah, Al, Wh[0], Wl[0], b[0], Ppk, nullptr, nullptr, n);
    // L2, L3
    for (int l = 1; l <= 2; ++l) {
        agg_packed<<<aggBlocks, 256, 0, stream>>>((const _Float16*)Ppk, row_ptr, esw, dinv, Ah, Al, n);
        gemm_wide<256, 0><<<gw, 256, 0, stream>>>(Ah, Al, Wh[l], Wl[l], b[l], Ppk, nullptr, nullptr, n);
    }
    // L4 -> planes
    agg_packed<<<aggBlocks, 256, 0, stream>>>((const _Float16*)Ppk, row_ptr, esw, dinv, Ah, Al, n);
    gemm_wide<256, 1><<<gw, 256, 0, stream>>>(Ah, Al, Wh[3], Wl[3], b[3], nullptr, Bh2, Bl2, n);
    // L5
    gemm_narrow<<<gn, 256, 0, stream>>>(Bh2, Bl2, Wh[4], Wl[4], scratch, n);
    agg_f32_64<<<(n + 3) / 4, 256, 0, stream>>>(scratch, row_ptr, esw, dinv, b[4], out, n);
}